// Round 5
// baseline (667.696 us; speedup 1.0000x reference)
//
#include <hip/hip_runtime.h>

#define D 128
#define D4 32      // fp32 row length in float4
#define CAPH 32    // slots per half-edge-set (half-degree ~Poisson(6); P(>32) ~ 1e-16)
#define PITER 5
#define GBLK 768   // persistent grid: 3 blocks/CU x 256 CUs, co-resident BY CONSTRUCTION
#define CHUNKS 9   // ceil(50000 / ((GBLK/2)*16)) node-halves per lane-group

typedef float v4f __attribute__((ext_vector_type(4)));
typedef _Float16 h4 __attribute__((ext_vector_type(4)));   // 8-byte fp16 quad

static inline size_t align_up(size_t v, size_t a) { return (v + a - 1) & ~(a - 1); }

// ---- split-contention ELL build (at raw atomic-rate floor, unchanged) ----
// packed*: bits[63:48]=count, bits[47:0]=sum(dist) Q16.32 (exact integer add).
__global__ void fill_ell_kernel(const int* __restrict__ src,
                                const int* __restrict__ dst,
                                const float* __restrict__ dist,
                                unsigned long long* __restrict__ packedA,
                                unsigned long long* __restrict__ packedB,
                                unsigned short* __restrict__ adjA,
                                unsigned short* __restrict__ adjB,
                                int E, int Ehalf) {
  int e = blockIdx.x * blockDim.x + threadIdx.x;
  if (e >= E) return;
  int s = src[e];
  unsigned long long fx = (unsigned long long)(dist[e] * 4294967296.0f);
  unsigned long long val = (1ull << 48) | fx;
  if (e < Ehalf) {
    unsigned long long old = atomicAdd(&packedA[s], val);
    unsigned int slot = (unsigned int)(old >> 48);
    if (slot < CAPH) adjA[(size_t)s * CAPH + slot] = (unsigned short)dst[e];
  } else {
    unsigned long long old = atomicAdd(&packedB[s], val);
    unsigned int slot = (unsigned int)(old >> 48);
    if (slot < CAPH) adjB[(size_t)s * CAPH + slot] = (unsigned short)dst[e];
  }
}

// ---- base = w1*x + w2*g + w4*relu(w5*distsum), fp16; seed uA = fp16(x);
// ---- zero dummy row N of uA/uB (clamped tail indices gather from it) ----
__global__ void base_seed_kernel(const v4f* __restrict__ x4, const v4f* __restrict__ g4,
                                 const unsigned long long* __restrict__ packedA,
                                 const unsigned long long* __restrict__ packedB,
                                 const float* __restrict__ w1p, const float* __restrict__ w2p,
                                 const float* __restrict__ w4p, const float* __restrict__ w5p,
                                 h4* __restrict__ base, h4* __restrict__ uA,
                                 h4* __restrict__ uB, int n) {
  int i = blockIdx.x * blockDim.x + threadIdx.x;
  int node = i >> 5;
  int lane = i & 31;
  if (node > n) return;
  size_t idx = (size_t)i;
  if (node == n) {           // dummy zero row
    h4 z = {0, 0, 0, 0};
    uA[idx] = z;
    uB[idx] = z;
    return;
  }
  v4f xv = x4[(size_t)node * D4 + lane];
  v4f gv = g4[lane];
  unsigned long long sum = (packedA[node] & 0xFFFFFFFFFFFFull)
                         + (packedB[node] & 0xFFFFFFFFFFFFull);
  float ds = (float)sum * (1.0f / 4294967296.0f);
  float t = w5p[0] * ds;
  t = t > 0.f ? t : 0.f;
  v4f b = w1p[0] * xv + w2p[0] * gv;
  b += t * w4p[0];
  base[idx] = __builtin_convertvector(b, h4);
  uA[idx] = __builtin_convertvector(xv, h4);
}

// ---- persistent propagation: all 5 iterations in ONE plain kernel ----
// Manual grid barrier (no cooperative API — it silently fails under the
// harness's graph capture; r3 post-mortem). One fresh counter per iteration
// boundary: arrive = device-scope atomicAdd; spin = agent-scope atomic load
// (sc1, reads LLC — immune to per-XCD L2 staleness). __threadfence() before
// arrive (L2 writeback) and after release (L2 invalidate) give the same
// cross-XCD visibility a launch boundary provides. All 768 blocks are
// co-resident by construction (launch_bounds(256,3), LDS=0, 3 blk/CU x 256).
__global__ __launch_bounds__(256, 3) void prop_persist_kernel(
    h4* __restrict__ uAb, h4* __restrict__ uBb,     // both written (ping-pong)
    const h4* __restrict__ base,
    const unsigned long long* __restrict__ packedA,
    const unsigned long long* __restrict__ packedB,
    const unsigned short* __restrict__ adjA,
    const unsigned short* __restrict__ adjB,
    const float* __restrict__ w3p,
    unsigned* __restrict__ bar,
    float* __restrict__ out, int n)
{
  int half  = blockIdx.x & 1;
  int bp    = blockIdx.x >> 1;
  int group = threadIdx.x >> 4;        // 16 node-groups per block
  int lane  = threadIdx.x & 15;        // 16 lanes per node-half
  int gg    = bp * 16 + group;         // 0 .. (GBLK/2)*16 - 1
  const int stride = (GBLK >> 1) * 16; // node-half stride between chunks

  float w3 = w3p[0];

  // ---- prologue: load iteration-invariant state into registers, once ----
  int a0[CHUNKS], a1[CHUNKS], b0[CHUNKS], b1[CHUNKS];
  int dgA[CHUNKS], dgB[CHUNKS];
  h4 bs[CHUNKS];
#pragma unroll
  for (int c = 0; c < CHUNKS; ++c) {
    int node = gg + c * stride;
    bool valid = node < n;
    int nd = valid ? node : 0;
    unsigned long long pA = packedA[nd];
    unsigned long long pB = packedB[nd];
    int dA = (int)(pA >> 48); if (dA > CAPH) dA = CAPH;
    int dB = (int)(pB >> 48); if (dB > CAPH) dB = CAPH;
    dgA[c] = valid ? dA : 0;
    dgB[c] = valid ? dB : 0;
    const unsigned short* rowA = adjA + (size_t)nd * CAPH;
    const unsigned short* rowB = adjB + (size_t)nd * CAPH;
    a0[c] = rowA[lane];
    a1[c] = rowA[lane + 16];
    b0[c] = rowB[lane];
    b1[c] = rowB[lane + 16];
    bs[c] = base[(size_t)nd * 32 + half * 16 + lane];
  }

  for (int it = 0; it < PITER; ++it) {
    const h4* uin = (it & 1) ? uBb : uAb;
    h4* uoutp     = (it & 1) ? uAb : uBb;
    const h4* uh  = uin + (size_t)half * 16 + lane;
    int last = (it == PITER - 1);

#pragma unroll
    for (int c = 0; c < CHUNKS; ++c) {
      int node = gg + c * stride;
      if (node >= n) break;            // group-uniform; later chunks also OOB
      int degA = dgA[c];
      int degB = dgB[c];

      v4f acc0 = {0.f,0.f,0.f,0.f}, acc1 = acc0, acc2 = acc0, acc3 = acc0;

      // common case: first 8 of set A AND first 8 of set B in flight
      {
        int jA0 = __shfl(a0[c], 0, 16); jA0 = (0 < degA) ? jA0 : n;
        int jA1 = __shfl(a0[c], 1, 16); jA1 = (1 < degA) ? jA1 : n;
        int jA2 = __shfl(a0[c], 2, 16); jA2 = (2 < degA) ? jA2 : n;
        int jA3 = __shfl(a0[c], 3, 16); jA3 = (3 < degA) ? jA3 : n;
        int jA4 = __shfl(a0[c], 4, 16); jA4 = (4 < degA) ? jA4 : n;
        int jA5 = __shfl(a0[c], 5, 16); jA5 = (5 < degA) ? jA5 : n;
        int jA6 = __shfl(a0[c], 6, 16); jA6 = (6 < degA) ? jA6 : n;
        int jA7 = __shfl(a0[c], 7, 16); jA7 = (7 < degA) ? jA7 : n;
        int jB0 = __shfl(b0[c], 0, 16); jB0 = (0 < degB) ? jB0 : n;
        int jB1 = __shfl(b0[c], 1, 16); jB1 = (1 < degB) ? jB1 : n;
        int jB2 = __shfl(b0[c], 2, 16); jB2 = (2 < degB) ? jB2 : n;
        int jB3 = __shfl(b0[c], 3, 16); jB3 = (3 < degB) ? jB3 : n;
        int jB4 = __shfl(b0[c], 4, 16); jB4 = (4 < degB) ? jB4 : n;
        int jB5 = __shfl(b0[c], 5, 16); jB5 = (5 < degB) ? jB5 : n;
        int jB6 = __shfl(b0[c], 6, 16); jB6 = (6 < degB) ? jB6 : n;
        int jB7 = __shfl(b0[c], 7, 16); jB7 = (7 < degB) ? jB7 : n;
        h4 vA0 = uh[(size_t)jA0 * 32];
        h4 vA1 = uh[(size_t)jA1 * 32];
        h4 vA2 = uh[(size_t)jA2 * 32];
        h4 vA3 = uh[(size_t)jA3 * 32];
        h4 vA4 = uh[(size_t)jA4 * 32];
        h4 vA5 = uh[(size_t)jA5 * 32];
        h4 vA6 = uh[(size_t)jA6 * 32];
        h4 vA7 = uh[(size_t)jA7 * 32];
        h4 vB0 = uh[(size_t)jB0 * 32];
        h4 vB1 = uh[(size_t)jB1 * 32];
        h4 vB2 = uh[(size_t)jB2 * 32];
        h4 vB3 = uh[(size_t)jB3 * 32];
        h4 vB4 = uh[(size_t)jB4 * 32];
        h4 vB5 = uh[(size_t)jB5 * 32];
        h4 vB6 = uh[(size_t)jB6 * 32];
        h4 vB7 = uh[(size_t)jB7 * 32];
        acc0 += __builtin_convertvector(vA0, v4f) + __builtin_convertvector(vA1, v4f);
        acc1 += __builtin_convertvector(vA2, v4f) + __builtin_convertvector(vA3, v4f);
        acc2 += __builtin_convertvector(vA4, v4f) + __builtin_convertvector(vA5, v4f);
        acc3 += __builtin_convertvector(vA6, v4f) + __builtin_convertvector(vA7, v4f);
        acc0 += __builtin_convertvector(vB0, v4f) + __builtin_convertvector(vB1, v4f);
        acc1 += __builtin_convertvector(vB2, v4f) + __builtin_convertvector(vB3, v4f);
        acc2 += __builtin_convertvector(vB4, v4f) + __builtin_convertvector(vB5, v4f);
        acc3 += __builtin_convertvector(vB6, v4f) + __builtin_convertvector(vB7, v4f);
      }

      // tails (P(deg>8) ~ 0.15 per set)
      for (int k = 8; k < degA; k += 8) {
        int sel = (k >= 16) ? a1[c] : a0[c];
        int j0 = __shfl(sel, (k + 0) & 15, 16); j0 = (k + 0 < degA) ? j0 : n;
        int j1 = __shfl(sel, (k + 1) & 15, 16); j1 = (k + 1 < degA) ? j1 : n;
        int j2 = __shfl(sel, (k + 2) & 15, 16); j2 = (k + 2 < degA) ? j2 : n;
        int j3 = __shfl(sel, (k + 3) & 15, 16); j3 = (k + 3 < degA) ? j3 : n;
        int j4 = __shfl(sel, (k + 4) & 15, 16); j4 = (k + 4 < degA) ? j4 : n;
        int j5 = __shfl(sel, (k + 5) & 15, 16); j5 = (k + 5 < degA) ? j5 : n;
        int j6 = __shfl(sel, (k + 6) & 15, 16); j6 = (k + 6 < degA) ? j6 : n;
        int j7 = __shfl(sel, (k + 7) & 15, 16); j7 = (k + 7 < degA) ? j7 : n;
        h4 v0 = uh[(size_t)j0 * 32];
        h4 v1 = uh[(size_t)j1 * 32];
        h4 v2 = uh[(size_t)j2 * 32];
        h4 v3 = uh[(size_t)j3 * 32];
        h4 v4 = uh[(size_t)j4 * 32];
        h4 v5 = uh[(size_t)j5 * 32];
        h4 v6 = uh[(size_t)j6 * 32];
        h4 v7 = uh[(size_t)j7 * 32];
        acc0 += __builtin_convertvector(v0, v4f) + __builtin_convertvector(v1, v4f);
        acc1 += __builtin_convertvector(v2, v4f) + __builtin_convertvector(v3, v4f);
        acc2 += __builtin_convertvector(v4, v4f) + __builtin_convertvector(v5, v4f);
        acc3 += __builtin_convertvector(v6, v4f) + __builtin_convertvector(v7, v4f);
      }
      for (int k = 8; k < degB; k += 8) {
        int sel = (k >= 16) ? b1[c] : b0[c];
        int j0 = __shfl(sel, (k + 0) & 15, 16); j0 = (k + 0 < degB) ? j0 : n;
        int j1 = __shfl(sel, (k + 1) & 15, 16); j1 = (k + 1 < degB) ? j1 : n;
        int j2 = __shfl(sel, (k + 2) & 15, 16); j2 = (k + 2 < degB) ? j2 : n;
        int j3 = __shfl(sel, (k + 3) & 15, 16); j3 = (k + 3 < degB) ? j3 : n;
        int j4 = __shfl(sel, (k + 4) & 15, 16); j4 = (k + 4 < degB) ? j4 : n;
        int j5 = __shfl(sel, (k + 5) & 15, 16); j5 = (k + 5 < degB) ? j5 : n;
        int j6 = __shfl(sel, (k + 6) & 15, 16); j6 = (k + 6 < degB) ? j6 : n;
        int j7 = __shfl(sel, (k + 7) & 15, 16); j7 = (k + 7 < degB) ? j7 : n;
        h4 v0 = uh[(size_t)j0 * 32];
        h4 v1 = uh[(size_t)j1 * 32];
        h4 v2 = uh[(size_t)j2 * 32];
        h4 v3 = uh[(size_t)j3 * 32];
        h4 v4 = uh[(size_t)j4 * 32];
        h4 v5 = uh[(size_t)j5 * 32];
        h4 v6 = uh[(size_t)j6 * 32];
        h4 v7 = uh[(size_t)j7 * 32];
        acc0 += __builtin_convertvector(v0, v4f) + __builtin_convertvector(v1, v4f);
        acc1 += __builtin_convertvector(v2, v4f) + __builtin_convertvector(v3, v4f);
        acc2 += __builtin_convertvector(v4, v4f) + __builtin_convertvector(v5, v4f);
        acc3 += __builtin_convertvector(v6, v4f) + __builtin_convertvector(v7, v4f);
      }

      v4f asum = (acc0 + acc1) + (acc2 + acc3);
      v4f r = __builtin_convertvector(bs[c], v4f) + w3 * asum;
      size_t idx = (size_t)node * 32 + half * 16 + lane;
      if (last) {
        r.x = r.x > 0.f ? r.x : 0.f;
        r.y = r.y > 0.f ? r.y : 0.f;
        r.z = r.z > 0.f ? r.z : 0.f;
        r.w = r.w > 0.f ? r.w : 0.f;
        __builtin_nontemporal_store(r, (v4f*)out + idx);
      } else {
        uoutp[idx] = __builtin_convertvector(r, h4);
      }
    }

    if (!last) {
      // ---- manual grid barrier #it (all GBLK blocks resident) ----
      __syncthreads();                     // block's stores issued & drained
      if (threadIdx.x == 0) {
        __threadfence();                   // agent fence: L2 writeback
        atomicAdd(&bar[it], 1u);           // device-scope arrive
        while (__hip_atomic_load(&bar[it], __ATOMIC_RELAXED,
                                 __HIP_MEMORY_SCOPE_AGENT) < (unsigned)GBLK)
          __builtin_amdgcn_s_sleep(2);     // sc1 load reads LLC (no stale L2)
        __threadfence();                   // agent fence: invalidate stale L2
      }
      __syncthreads();                     // rest of block waits on lane 0
    }
  }
}

extern "C" void kernel_launch(void* const* d_in, const int* in_sizes, int n_in,
                              void* d_out, int out_size, void* d_ws, size_t ws_size,
                              hipStream_t stream) {
  const float* x    = (const float*)d_in[0];
  const float* g    = (const float*)d_in[1];
  const float* dist = (const float*)d_in[2];
  const float* w1   = (const float*)d_in[3];
  const float* w2   = (const float*)d_in[4];
  const float* w3   = (const float*)d_in[5];
  const float* w4   = (const float*)d_in[6];
  const float* w5   = (const float*)d_in[7];
  const int*   src  = (const int*)d_in[8];
  const int*   dst  = (const int*)d_in[9];

  const int N = in_sizes[0] / D;
  const int E = in_sizes[2];
  const int Ehalf = E / 2;

  // ---- workspace carve: packedA+packedB+barriers adjacent (one memset) ----
  char* ws = (char*)d_ws;
  size_t o = 0;
  unsigned long long* packedA = (unsigned long long*)(ws + o); o += align_up((size_t)N * 8, 256);
  unsigned long long* packedB = (unsigned long long*)(ws + o); o += align_up((size_t)N * 8, 256);
  unsigned* bar = (unsigned*)(ws + o);
  size_t zero_end = o + 256;               // 4 barrier counters (+pad)
  o += 256;
  unsigned short* adjA = (unsigned short*)(ws + o); o += align_up((size_t)N * CAPH * 2, 256);
  unsigned short* adjB = (unsigned short*)(ws + o); o += align_up((size_t)N * CAPH * 2, 256);
  h4* baseB = (h4*)(ws + o); o += align_up((size_t)(N + 1) * D * 2, 256);
  h4* uA    = (h4*)(ws + o); o += align_up((size_t)(N + 1) * D * 2, 256);
  h4* uB    = (h4*)(ws + o); o += align_up((size_t)(N + 1) * D * 2, 256);
  float* out = (float*)d_out;

  hipMemsetAsync(ws, 0, zero_end, stream); // zero packedA+packedB+bar (0.8 MB)

  const int tb = 256;
  const int eblocks = (E + tb - 1) / tb;
  const int sthreads = (N + 1) * 32;
  const int sblocks = (sthreads + tb - 1) / tb;

  fill_ell_kernel<<<eblocks, tb, 0, stream>>>(src, dst, dist, packedA, packedB,
                                              adjA, adjB, E, Ehalf);
  base_seed_kernel<<<sblocks, tb, 0, stream>>>((const v4f*)x, (const v4f*)g,
                                               packedA, packedB,
                                               w1, w2, w4, w5, baseB, uA, uB, N);

  // one persistent kernel runs all 5 propagation iterations (manual barrier)
  prop_persist_kernel<<<GBLK, 256, 0, stream>>>(uA, uB, baseB, packedA, packedB,
                                                adjA, adjB, w3, bar, out, N);
}

// Round 6
// 660.458 us; speedup vs baseline: 1.0110x; 1.0110x over previous
//
#include <hip/hip_runtime.h>

#define D 128
#define D4 32      // fp32 row length in float4
#define CAPH 32    // slots per half-edge-set (half-degree ~Poisson(6); P(>32) ~ 1e-16)
#define PITER 5
#define GBLK 768   // persistent grid: 3 blocks/CU x 256 CUs, co-resident BY CONSTRUCTION
#define CHUNKS 9   // ceil(50000 / ((GBLK/2)*16)) node-halves per lane-group

typedef float v4f __attribute__((ext_vector_type(4)));
typedef _Float16 h4 __attribute__((ext_vector_type(4)));   // 8-byte fp16 quad

static inline size_t align_up(size_t v, size_t a) { return (v + a - 1) & ~(a - 1); }

// ---- split-contention ELL build (at raw atomic-rate floor, unchanged) ----
// packed*: bits[63:48]=count, bits[47:0]=sum(dist) Q16.32 (exact integer add).
__global__ void fill_ell_kernel(const int* __restrict__ src,
                                const int* __restrict__ dst,
                                const float* __restrict__ dist,
                                unsigned long long* __restrict__ packedA,
                                unsigned long long* __restrict__ packedB,
                                unsigned short* __restrict__ adjA,
                                unsigned short* __restrict__ adjB,
                                int E, int Ehalf) {
  int e = blockIdx.x * blockDim.x + threadIdx.x;
  if (e >= E) return;
  int s = src[e];
  unsigned long long fx = (unsigned long long)(dist[e] * 4294967296.0f);
  unsigned long long val = (1ull << 48) | fx;
  if (e < Ehalf) {
    unsigned long long old = atomicAdd(&packedA[s], val);
    unsigned int slot = (unsigned int)(old >> 48);
    if (slot < CAPH) adjA[(size_t)s * CAPH + slot] = (unsigned short)dst[e];
  } else {
    unsigned long long old = atomicAdd(&packedB[s], val);
    unsigned int slot = (unsigned int)(old >> 48);
    if (slot < CAPH) adjB[(size_t)s * CAPH + slot] = (unsigned short)dst[e];
  }
}

// ---- base = w1*x + w2*g + w4*relu(w5*distsum), fp16; seed uA = fp16(x);
// ---- zero dummy row N of uA/uB (clamped tail indices gather from it) ----
__global__ void base_seed_kernel(const v4f* __restrict__ x4, const v4f* __restrict__ g4,
                                 const unsigned long long* __restrict__ packedA,
                                 const unsigned long long* __restrict__ packedB,
                                 const float* __restrict__ w1p, const float* __restrict__ w2p,
                                 const float* __restrict__ w4p, const float* __restrict__ w5p,
                                 h4* __restrict__ base, h4* __restrict__ uA,
                                 h4* __restrict__ uB, int n) {
  int i = blockIdx.x * blockDim.x + threadIdx.x;
  int node = i >> 5;
  int lane = i & 31;
  if (node > n) return;
  size_t idx = (size_t)i;
  if (node == n) {           // dummy zero row
    h4 z = {0, 0, 0, 0};
    uA[idx] = z;
    uB[idx] = z;
    return;
  }
  v4f xv = x4[(size_t)node * D4 + lane];
  v4f gv = g4[lane];
  unsigned long long sum = (packedA[node] & 0xFFFFFFFFFFFFull)
                         + (packedB[node] & 0xFFFFFFFFFFFFull);
  float ds = (float)sum * (1.0f / 4294967296.0f);
  float t = w5p[0] * ds;
  t = t > 0.f ? t : 0.f;
  v4f b = w1p[0] * xv + w2p[0] * gv;
  b += t * w4p[0];
  base[idx] = __builtin_convertvector(b, h4);
  uA[idx] = __builtin_convertvector(xv, h4);
}

// ---- persistent propagation: all 5 iterations in ONE plain kernel ----
// Manual grid barrier (cooperative API fails under graph capture; r3).
// r4 post-mortem: `break` inside the unrolled chunk loop blocked full unroll
// -> per-chunk state arrays went to SCRATCH (VGPR=84, FETCH 3x expected).
// Fix: constant trip count, per-chunk `if (node < n)` guard, NO break ->
// full unroll -> compile-time indices -> all state in registers.
__global__ __launch_bounds__(256, 3) void prop_persist_kernel(
    h4* __restrict__ uAb, h4* __restrict__ uBb,     // both written (ping-pong)
    const h4* __restrict__ base,
    const unsigned long long* __restrict__ packedA,
    const unsigned long long* __restrict__ packedB,
    const unsigned short* __restrict__ adjA,
    const unsigned short* __restrict__ adjB,
    const float* __restrict__ w3p,
    unsigned* __restrict__ bar,
    float* __restrict__ out, int n)
{
  int half  = blockIdx.x & 1;
  int bp    = blockIdx.x >> 1;
  int group = threadIdx.x >> 4;        // 16 node-groups per block
  int lane  = threadIdx.x & 15;        // 16 lanes per node-half
  int gg    = bp * 16 + group;         // 0 .. (GBLK/2)*16 - 1
  const int stride = (GBLK >> 1) * 16; // node-half stride between chunks

  float w3 = w3p[0];

  // ---- prologue: load iteration-invariant state into registers, once ----
  int a0[CHUNKS], a1[CHUNKS], b0[CHUNKS], b1[CHUNKS];
  int dgA[CHUNKS], dgB[CHUNKS];
  h4 bs[CHUNKS];
#pragma unroll
  for (int c = 0; c < CHUNKS; ++c) {
    int node = gg + c * stride;
    bool valid = node < n;
    int nd = valid ? node : 0;
    unsigned long long pA = packedA[nd];
    unsigned long long pB = packedB[nd];
    int dA = (int)(pA >> 48); if (dA > CAPH) dA = CAPH;
    int dB = (int)(pB >> 48); if (dB > CAPH) dB = CAPH;
    dgA[c] = valid ? dA : 0;
    dgB[c] = valid ? dB : 0;
    const unsigned short* rowA = adjA + (size_t)nd * CAPH;
    const unsigned short* rowB = adjB + (size_t)nd * CAPH;
    a0[c] = rowA[lane];
    a1[c] = rowA[lane + 16];
    b0[c] = rowB[lane];
    b1[c] = rowB[lane + 16];
    bs[c] = base[(size_t)nd * 32 + half * 16 + lane];
  }

  for (int it = 0; it < PITER; ++it) {
    const h4* uin = (it & 1) ? uBb : uAb;
    h4* uoutp     = (it & 1) ? uAb : uBb;
    const h4* uh  = uin + (size_t)half * 16 + lane;
    int last = (it == PITER - 1);

#pragma unroll
    for (int c = 0; c < CHUNKS; ++c) {      // constant 9-trip, NO break ->
      int node = gg + c * stride;           // full unroll, static indices
      if (node < n) {
        int degA = dgA[c];
        int degB = dgB[c];

        v4f acc0 = {0.f,0.f,0.f,0.f}, acc1 = acc0, acc2 = acc0, acc3 = acc0;

        // common case: first 8 of set A AND first 8 of set B in flight
        {
          int jA0 = __shfl(a0[c], 0, 16); jA0 = (0 < degA) ? jA0 : n;
          int jA1 = __shfl(a0[c], 1, 16); jA1 = (1 < degA) ? jA1 : n;
          int jA2 = __shfl(a0[c], 2, 16); jA2 = (2 < degA) ? jA2 : n;
          int jA3 = __shfl(a0[c], 3, 16); jA3 = (3 < degA) ? jA3 : n;
          int jA4 = __shfl(a0[c], 4, 16); jA4 = (4 < degA) ? jA4 : n;
          int jA5 = __shfl(a0[c], 5, 16); jA5 = (5 < degA) ? jA5 : n;
          int jA6 = __shfl(a0[c], 6, 16); jA6 = (6 < degA) ? jA6 : n;
          int jA7 = __shfl(a0[c], 7, 16); jA7 = (7 < degA) ? jA7 : n;
          int jB0 = __shfl(b0[c], 0, 16); jB0 = (0 < degB) ? jB0 : n;
          int jB1 = __shfl(b0[c], 1, 16); jB1 = (1 < degB) ? jB1 : n;
          int jB2 = __shfl(b0[c], 2, 16); jB2 = (2 < degB) ? jB2 : n;
          int jB3 = __shfl(b0[c], 3, 16); jB3 = (3 < degB) ? jB3 : n;
          int jB4 = __shfl(b0[c], 4, 16); jB4 = (4 < degB) ? jB4 : n;
          int jB5 = __shfl(b0[c], 5, 16); jB5 = (5 < degB) ? jB5 : n;
          int jB6 = __shfl(b0[c], 6, 16); jB6 = (6 < degB) ? jB6 : n;
          int jB7 = __shfl(b0[c], 7, 16); jB7 = (7 < degB) ? jB7 : n;
          h4 vA0 = uh[(size_t)jA0 * 32];
          h4 vA1 = uh[(size_t)jA1 * 32];
          h4 vA2 = uh[(size_t)jA2 * 32];
          h4 vA3 = uh[(size_t)jA3 * 32];
          h4 vA4 = uh[(size_t)jA4 * 32];
          h4 vA5 = uh[(size_t)jA5 * 32];
          h4 vA6 = uh[(size_t)jA6 * 32];
          h4 vA7 = uh[(size_t)jA7 * 32];
          h4 vB0 = uh[(size_t)jB0 * 32];
          h4 vB1 = uh[(size_t)jB1 * 32];
          h4 vB2 = uh[(size_t)jB2 * 32];
          h4 vB3 = uh[(size_t)jB3 * 32];
          h4 vB4 = uh[(size_t)jB4 * 32];
          h4 vB5 = uh[(size_t)jB5 * 32];
          h4 vB6 = uh[(size_t)jB6 * 32];
          h4 vB7 = uh[(size_t)jB7 * 32];
          acc0 += __builtin_convertvector(vA0, v4f) + __builtin_convertvector(vA1, v4f);
          acc1 += __builtin_convertvector(vA2, v4f) + __builtin_convertvector(vA3, v4f);
          acc2 += __builtin_convertvector(vA4, v4f) + __builtin_convertvector(vA5, v4f);
          acc3 += __builtin_convertvector(vA6, v4f) + __builtin_convertvector(vA7, v4f);
          acc0 += __builtin_convertvector(vB0, v4f) + __builtin_convertvector(vB1, v4f);
          acc1 += __builtin_convertvector(vB2, v4f) + __builtin_convertvector(vB3, v4f);
          acc2 += __builtin_convertvector(vB4, v4f) + __builtin_convertvector(vB5, v4f);
          acc3 += __builtin_convertvector(vB6, v4f) + __builtin_convertvector(vB7, v4f);
        }

        // tails (P(deg>8) ~ 0.15 per set)
        for (int k = 8; k < degA; k += 8) {
          int sel = (k >= 16) ? a1[c] : a0[c];
          int j0 = __shfl(sel, (k + 0) & 15, 16); j0 = (k + 0 < degA) ? j0 : n;
          int j1 = __shfl(sel, (k + 1) & 15, 16); j1 = (k + 1 < degA) ? j1 : n;
          int j2 = __shfl(sel, (k + 2) & 15, 16); j2 = (k + 2 < degA) ? j2 : n;
          int j3 = __shfl(sel, (k + 3) & 15, 16); j3 = (k + 3 < degA) ? j3 : n;
          int j4 = __shfl(sel, (k + 4) & 15, 16); j4 = (k + 4 < degA) ? j4 : n;
          int j5 = __shfl(sel, (k + 5) & 15, 16); j5 = (k + 5 < degA) ? j5 : n;
          int j6 = __shfl(sel, (k + 6) & 15, 16); j6 = (k + 6 < degA) ? j6 : n;
          int j7 = __shfl(sel, (k + 7) & 15, 16); j7 = (k + 7 < degA) ? j7 : n;
          h4 v0 = uh[(size_t)j0 * 32];
          h4 v1 = uh[(size_t)j1 * 32];
          h4 v2 = uh[(size_t)j2 * 32];
          h4 v3 = uh[(size_t)j3 * 32];
          h4 v4 = uh[(size_t)j4 * 32];
          h4 v5 = uh[(size_t)j5 * 32];
          h4 v6 = uh[(size_t)j6 * 32];
          h4 v7 = uh[(size_t)j7 * 32];
          acc0 += __builtin_convertvector(v0, v4f) + __builtin_convertvector(v1, v4f);
          acc1 += __builtin_convertvector(v2, v4f) + __builtin_convertvector(v3, v4f);
          acc2 += __builtin_convertvector(v4, v4f) + __builtin_convertvector(v5, v4f);
          acc3 += __builtin_convertvector(v6, v4f) + __builtin_convertvector(v7, v4f);
        }
        for (int k = 8; k < degB; k += 8) {
          int sel = (k >= 16) ? b1[c] : b0[c];
          int j0 = __shfl(sel, (k + 0) & 15, 16); j0 = (k + 0 < degB) ? j0 : n;
          int j1 = __shfl(sel, (k + 1) & 15, 16); j1 = (k + 1 < degB) ? j1 : n;
          int j2 = __shfl(sel, (k + 2) & 15, 16); j2 = (k + 2 < degB) ? j2 : n;
          int j3 = __shfl(sel, (k + 3) & 15, 16); j3 = (k + 3 < degB) ? j3 : n;
          int j4 = __shfl(sel, (k + 4) & 15, 16); j4 = (k + 4 < degB) ? j4 : n;
          int j5 = __shfl(sel, (k + 5) & 15, 16); j5 = (k + 5 < degB) ? j5 : n;
          int j6 = __shfl(sel, (k + 6) & 15, 16); j6 = (k + 6 < degB) ? j6 : n;
          int j7 = __shfl(sel, (k + 7) & 15, 16); j7 = (k + 7 < degB) ? j7 : n;
          h4 v0 = uh[(size_t)j0 * 32];
          h4 v1 = uh[(size_t)j1 * 32];
          h4 v2 = uh[(size_t)j2 * 32];
          h4 v3 = uh[(size_t)j3 * 32];
          h4 v4 = uh[(size_t)j4 * 32];
          h4 v5 = uh[(size_t)j5 * 32];
          h4 v6 = uh[(size_t)j6 * 32];
          h4 v7 = uh[(size_t)j7 * 32];
          acc0 += __builtin_convertvector(v0, v4f) + __builtin_convertvector(v1, v4f);
          acc1 += __builtin_convertvector(v2, v4f) + __builtin_convertvector(v3, v4f);
          acc2 += __builtin_convertvector(v4, v4f) + __builtin_convertvector(v5, v4f);
          acc3 += __builtin_convertvector(v6, v4f) + __builtin_convertvector(v7, v4f);
        }

        v4f asum = (acc0 + acc1) + (acc2 + acc3);
        v4f r = __builtin_convertvector(bs[c], v4f) + w3 * asum;
        size_t idx = (size_t)node * 32 + half * 16 + lane;
        if (last) {
          r.x = r.x > 0.f ? r.x : 0.f;
          r.y = r.y > 0.f ? r.y : 0.f;
          r.z = r.z > 0.f ? r.z : 0.f;
          r.w = r.w > 0.f ? r.w : 0.f;
          __builtin_nontemporal_store(r, (v4f*)out + idx);
        } else {
          uoutp[idx] = __builtin_convertvector(r, h4);
        }
      }
    }

    if (!last) {
      // ---- manual grid barrier #it (all GBLK blocks resident) ----
      __syncthreads();                     // block's stores issued & drained
      if (threadIdx.x == 0) {
        __threadfence();                   // agent fence: L2 writeback
        atomicAdd(&bar[it], 1u);           // device-scope arrive
        while (__hip_atomic_load(&bar[it], __ATOMIC_RELAXED,
                                 __HIP_MEMORY_SCOPE_AGENT) < (unsigned)GBLK)
          __builtin_amdgcn_s_sleep(2);     // sc1 load reads LLC (no stale L2)
        __threadfence();                   // agent fence: invalidate stale L2
      }
      __syncthreads();                     // rest of block waits on lane 0
    }
  }
}

extern "C" void kernel_launch(void* const* d_in, const int* in_sizes, int n_in,
                              void* d_out, int out_size, void* d_ws, size_t ws_size,
                              hipStream_t stream) {
  const float* x    = (const float*)d_in[0];
  const float* g    = (const float*)d_in[1];
  const float* dist = (const float*)d_in[2];
  const float* w1   = (const float*)d_in[3];
  const float* w2   = (const float*)d_in[4];
  const float* w3   = (const float*)d_in[5];
  const float* w4   = (const float*)d_in[6];
  const float* w5   = (const float*)d_in[7];
  const int*   src  = (const int*)d_in[8];
  const int*   dst  = (const int*)d_in[9];

  const int N = in_sizes[0] / D;
  const int E = in_sizes[2];
  const int Ehalf = E / 2;

  // ---- workspace carve: packedA+packedB+barriers adjacent (one memset) ----
  char* ws = (char*)d_ws;
  size_t o = 0;
  unsigned long long* packedA = (unsigned long long*)(ws + o); o += align_up((size_t)N * 8, 256);
  unsigned long long* packedB = (unsigned long long*)(ws + o); o += align_up((size_t)N * 8, 256);
  unsigned* bar = (unsigned*)(ws + o);
  size_t zero_end = o + 256;               // 4 barrier counters (+pad)
  o += 256;
  unsigned short* adjA = (unsigned short*)(ws + o); o += align_up((size_t)N * CAPH * 2, 256);
  unsigned short* adjB = (unsigned short*)(ws + o); o += align_up((size_t)N * CAPH * 2, 256);
  h4* baseB = (h4*)(ws + o); o += align_up((size_t)(N + 1) * D * 2, 256);
  h4* uA    = (h4*)(ws + o); o += align_up((size_t)(N + 1) * D * 2, 256);
  h4* uB    = (h4*)(ws + o); o += align_up((size_t)(N + 1) * D * 2, 256);
  float* out = (float*)d_out;

  hipMemsetAsync(ws, 0, zero_end, stream); // zero packedA+packedB+bar (0.8 MB)

  const int tb = 256;
  const int eblocks = (E + tb - 1) / tb;
  const int sthreads = (N + 1) * 32;
  const int sblocks = (sthreads + tb - 1) / tb;

  fill_ell_kernel<<<eblocks, tb, 0, stream>>>(src, dst, dist, packedA, packedB,
                                              adjA, adjB, E, Ehalf);
  base_seed_kernel<<<sblocks, tb, 0, stream>>>((const v4f*)x, (const v4f*)g,
                                               packedA, packedB,
                                               w1, w2, w4, w5, baseB, uA, uB, N);

  // one persistent kernel runs all 5 propagation iterations (manual barrier)
  prop_persist_kernel<<<GBLK, 256, 0, stream>>>(uA, uB, baseB, packedA, packedB,
                                                adjA, adjB, w3, bar, out, N);
}

// Round 7
// 252.469 us; speedup vs baseline: 2.6447x; 2.6160x over previous
//
#include <hip/hip_runtime.h>

#define D 128
#define D4 32      // fp32 row length in float4
#define CAPH 32    // slots per half-edge-set (half-degree ~Poisson(6); P(>32) ~ 1e-16)

typedef float v4f __attribute__((ext_vector_type(4)));
typedef _Float16 h4 __attribute__((ext_vector_type(4)));   // 8-byte fp16 quad

static inline size_t align_up(size_t v, size_t a) { return (v + a - 1) & ~(a - 1); }

// ---- split-contention ELL build (at raw atomic-rate floor, unchanged) ----
// packed*: bits[63:48]=count, bits[47:0]=sum(dist) Q16.32 (exact integer add).
__global__ void fill_ell_kernel(const int* __restrict__ src,
                                const int* __restrict__ dst,
                                const float* __restrict__ dist,
                                unsigned long long* __restrict__ packedA,
                                unsigned long long* __restrict__ packedB,
                                unsigned short* __restrict__ adjA,
                                unsigned short* __restrict__ adjB,
                                int E, int Ehalf) {
  int e = blockIdx.x * blockDim.x + threadIdx.x;
  if (e >= E) return;
  int s = src[e];
  unsigned long long fx = (unsigned long long)(dist[e] * 4294967296.0f);
  unsigned long long val = (1ull << 48) | fx;
  if (e < Ehalf) {
    unsigned long long old = atomicAdd(&packedA[s], val);
    unsigned int slot = (unsigned int)(old >> 48);
    if (slot < CAPH) adjA[(size_t)s * CAPH + slot] = (unsigned short)dst[e];
  } else {
    unsigned long long old = atomicAdd(&packedB[s], val);
    unsigned int slot = (unsigned int)(old >> 48);
    if (slot < CAPH) adjB[(size_t)s * CAPH + slot] = (unsigned short)dst[e];
  }
}

// ---- base = w1*x + w2*g + w4*relu(w5*distsum), fp16; seed uA = fp16(x);
// ---- zero dummy row N of uA/uB (clamped tail indices gather from it) ----
__global__ void base_seed_kernel(const v4f* __restrict__ x4, const v4f* __restrict__ g4,
                                 const unsigned long long* __restrict__ packedA,
                                 const unsigned long long* __restrict__ packedB,
                                 const float* __restrict__ w1p, const float* __restrict__ w2p,
                                 const float* __restrict__ w4p, const float* __restrict__ w5p,
                                 h4* __restrict__ base, h4* __restrict__ uA,
                                 h4* __restrict__ uB, int n) {
  int i = blockIdx.x * blockDim.x + threadIdx.x;
  int node = i >> 5;
  int lane = i & 31;
  if (node > n) return;
  size_t idx = (size_t)i;
  if (node == n) {           // dummy zero row
    h4 z = {0, 0, 0, 0};
    uA[idx] = z;
    uB[idx] = z;
    return;
  }
  v4f xv = x4[(size_t)node * D4 + lane];
  v4f gv = g4[lane];
  unsigned long long sum = (packedA[node] & 0xFFFFFFFFFFFFull)
                         + (packedB[node] & 0xFFFFFFFFFFFFull);
  float ds = (float)sum * (1.0f / 4294967296.0f);
  float t = w5p[0] * ds;
  t = t > 0.f ? t : 0.f;
  v4f b = w1p[0] * xv + w2p[0] * gv;
  b += t * w4p[0];
  base[idx] = __builtin_convertvector(b, h4);
  uA[idx] = __builtin_convertvector(xv, h4);
}

// ---- propagation, half-row (128B) XCD-partitioned (PROVEN layout) ----
// Block = (node chunk, feature half); half = blockIdx&1. With blockIdx%8 ->
// XCD round-robin, each XCD touches exactly ONE 128B line of any u row.
// 16 lanes per node-half, gather request = 16 x 8B contiguous = one full line.
// First 8 A-gathers and first 8 B-gathers issued together (16 lines in
// flight in the common deg<=8 case); base row load hoisted early.
__global__ __launch_bounds__(256) void prop_kernel(
    const h4* __restrict__ uin, const h4* __restrict__ base,
    const unsigned long long* __restrict__ packedA,
    const unsigned long long* __restrict__ packedB,
    const unsigned short* __restrict__ adjA,
    const unsigned short* __restrict__ adjB,
    const float* __restrict__ w3p,
    void* __restrict__ uout, int n, int final_relu)
{
  int half  = blockIdx.x & 1;
  int chunk = blockIdx.x >> 1;
  int group = threadIdx.x >> 4;        // 16 node-groups per block
  int lane  = threadIdx.x & 15;        // 16 lanes per node-half
  int node  = chunk * 16 + group;
  if (node >= n) return;

  unsigned long long pA = packedA[node];
  unsigned long long pB = packedB[node];
  int degA = (int)(pA >> 48); if (degA > CAPH) degA = CAPH;
  int degB = (int)(pB >> 48); if (degB > CAPH) degB = CAPH;

  // preload adjacency: set A slots 0..31 in a0/a1, set B in b0/b1
  const unsigned short* rowA = adjA + (size_t)node * CAPH;
  const unsigned short* rowB = adjB + (size_t)node * CAPH;
  int a0 = rowA[lane];
  int a1 = rowA[lane + 16];
  int b0 = rowB[lane];
  int b1 = rowB[lane + 16];

  // element offset within a row for this (half, lane): h4 units
  const h4* uh = uin + (size_t)half * 16 + lane;
  size_t idx = (size_t)node * 32 + half * 16 + lane;   // h4 / v4f units
  v4f bb = __builtin_convertvector(base[idx], v4f);    // overlaps gather chain

  v4f acc0 = {0.f,0.f,0.f,0.f}, acc1 = acc0, acc2 = acc0, acc3 = acc0;

  // ---- common case: first 8 of set A AND first 8 of set B in flight ----
  {
    int jA0 = __shfl(a0, 0, 16); jA0 = (0 < degA) ? jA0 : n;
    int jA1 = __shfl(a0, 1, 16); jA1 = (1 < degA) ? jA1 : n;
    int jA2 = __shfl(a0, 2, 16); jA2 = (2 < degA) ? jA2 : n;
    int jA3 = __shfl(a0, 3, 16); jA3 = (3 < degA) ? jA3 : n;
    int jA4 = __shfl(a0, 4, 16); jA4 = (4 < degA) ? jA4 : n;
    int jA5 = __shfl(a0, 5, 16); jA5 = (5 < degA) ? jA5 : n;
    int jA6 = __shfl(a0, 6, 16); jA6 = (6 < degA) ? jA6 : n;
    int jA7 = __shfl(a0, 7, 16); jA7 = (7 < degA) ? jA7 : n;
    int jB0 = __shfl(b0, 0, 16); jB0 = (0 < degB) ? jB0 : n;
    int jB1 = __shfl(b0, 1, 16); jB1 = (1 < degB) ? jB1 : n;
    int jB2 = __shfl(b0, 2, 16); jB2 = (2 < degB) ? jB2 : n;
    int jB3 = __shfl(b0, 3, 16); jB3 = (3 < degB) ? jB3 : n;
    int jB4 = __shfl(b0, 4, 16); jB4 = (4 < degB) ? jB4 : n;
    int jB5 = __shfl(b0, 5, 16); jB5 = (5 < degB) ? jB5 : n;
    int jB6 = __shfl(b0, 6, 16); jB6 = (6 < degB) ? jB6 : n;
    int jB7 = __shfl(b0, 7, 16); jB7 = (7 < degB) ? jB7 : n;
    h4 vA0 = uh[(size_t)jA0 * 32];
    h4 vA1 = uh[(size_t)jA1 * 32];
    h4 vA2 = uh[(size_t)jA2 * 32];
    h4 vA3 = uh[(size_t)jA3 * 32];
    h4 vA4 = uh[(size_t)jA4 * 32];
    h4 vA5 = uh[(size_t)jA5 * 32];
    h4 vA6 = uh[(size_t)jA6 * 32];
    h4 vA7 = uh[(size_t)jA7 * 32];
    h4 vB0 = uh[(size_t)jB0 * 32];
    h4 vB1 = uh[(size_t)jB1 * 32];
    h4 vB2 = uh[(size_t)jB2 * 32];
    h4 vB3 = uh[(size_t)jB3 * 32];
    h4 vB4 = uh[(size_t)jB4 * 32];
    h4 vB5 = uh[(size_t)jB5 * 32];
    h4 vB6 = uh[(size_t)jB6 * 32];
    h4 vB7 = uh[(size_t)jB7 * 32];
    acc0 += __builtin_convertvector(vA0, v4f) + __builtin_convertvector(vA1, v4f);
    acc1 += __builtin_convertvector(vA2, v4f) + __builtin_convertvector(vA3, v4f);
    acc2 += __builtin_convertvector(vA4, v4f) + __builtin_convertvector(vA5, v4f);
    acc3 += __builtin_convertvector(vA6, v4f) + __builtin_convertvector(vA7, v4f);
    acc0 += __builtin_convertvector(vB0, v4f) + __builtin_convertvector(vB1, v4f);
    acc1 += __builtin_convertvector(vB2, v4f) + __builtin_convertvector(vB3, v4f);
    acc2 += __builtin_convertvector(vB4, v4f) + __builtin_convertvector(vB5, v4f);
    acc3 += __builtin_convertvector(vB6, v4f) + __builtin_convertvector(vB7, v4f);
  }

  // ---- tails (P(deg>8) ~ 0.15 per set) ----
  for (int k = 8; k < degA; k += 8) {
    int sel = (k >= 16) ? a1 : a0;
    int j0 = __shfl(sel, (k + 0) & 15, 16); j0 = (k + 0 < degA) ? j0 : n;
    int j1 = __shfl(sel, (k + 1) & 15, 16); j1 = (k + 1 < degA) ? j1 : n;
    int j2 = __shfl(sel, (k + 2) & 15, 16); j2 = (k + 2 < degA) ? j2 : n;
    int j3 = __shfl(sel, (k + 3) & 15, 16); j3 = (k + 3 < degA) ? j3 : n;
    int j4 = __shfl(sel, (k + 4) & 15, 16); j4 = (k + 4 < degA) ? j4 : n;
    int j5 = __shfl(sel, (k + 5) & 15, 16); j5 = (k + 5 < degA) ? j5 : n;
    int j6 = __shfl(sel, (k + 6) & 15, 16); j6 = (k + 6 < degA) ? j6 : n;
    int j7 = __shfl(sel, (k + 7) & 15, 16); j7 = (k + 7 < degA) ? j7 : n;
    h4 v0 = uh[(size_t)j0 * 32];
    h4 v1 = uh[(size_t)j1 * 32];
    h4 v2 = uh[(size_t)j2 * 32];
    h4 v3 = uh[(size_t)j3 * 32];
    h4 v4 = uh[(size_t)j4 * 32];
    h4 v5 = uh[(size_t)j5 * 32];
    h4 v6 = uh[(size_t)j6 * 32];
    h4 v7 = uh[(size_t)j7 * 32];
    acc0 += __builtin_convertvector(v0, v4f) + __builtin_convertvector(v1, v4f);
    acc1 += __builtin_convertvector(v2, v4f) + __builtin_convertvector(v3, v4f);
    acc2 += __builtin_convertvector(v4, v4f) + __builtin_convertvector(v5, v4f);
    acc3 += __builtin_convertvector(v6, v4f) + __builtin_convertvector(v7, v4f);
  }
  for (int k = 8; k < degB; k += 8) {
    int sel = (k >= 16) ? b1 : b0;
    int j0 = __shfl(sel, (k + 0) & 15, 16); j0 = (k + 0 < degB) ? j0 : n;
    int j1 = __shfl(sel, (k + 1) & 15, 16); j1 = (k + 1 < degB) ? j1 : n;
    int j2 = __shfl(sel, (k + 2) & 15, 16); j2 = (k + 2 < degB) ? j2 : n;
    int j3 = __shfl(sel, (k + 3) & 15, 16); j3 = (k + 3 < degB) ? j3 : n;
    int j4 = __shfl(sel, (k + 4) & 15, 16); j4 = (k + 4 < degB) ? j4 : n;
    int j5 = __shfl(sel, (k + 5) & 15, 16); j5 = (k + 5 < degB) ? j5 : n;
    int j6 = __shfl(sel, (k + 6) & 15, 16); j6 = (k + 6 < degB) ? j6 : n;
    int j7 = __shfl(sel, (k + 7) & 15, 16); j7 = (k + 7 < degB) ? j7 : n;
    h4 v0 = uh[(size_t)j0 * 32];
    h4 v1 = uh[(size_t)j1 * 32];
    h4 v2 = uh[(size_t)j2 * 32];
    h4 v3 = uh[(size_t)j3 * 32];
    h4 v4 = uh[(size_t)j4 * 32];
    h4 v5 = uh[(size_t)j5 * 32];
    h4 v6 = uh[(size_t)j6 * 32];
    h4 v7 = uh[(size_t)j7 * 32];
    acc0 += __builtin_convertvector(v0, v4f) + __builtin_convertvector(v1, v4f);
    acc1 += __builtin_convertvector(v2, v4f) + __builtin_convertvector(v3, v4f);
    acc2 += __builtin_convertvector(v4, v4f) + __builtin_convertvector(v5, v4f);
    acc3 += __builtin_convertvector(v6, v4f) + __builtin_convertvector(v7, v4f);
  }
  v4f asum = (acc0 + acc1) + (acc2 + acc3);
  v4f r = bb + w3p[0] * asum;

  if (final_relu) {
    r.x = r.x > 0.f ? r.x : 0.f;
    r.y = r.y > 0.f ? r.y : 0.f;
    r.z = r.z > 0.f ? r.z : 0.f;
    r.w = r.w > 0.f ? r.w : 0.f;
    __builtin_nontemporal_store(r, (v4f*)uout + idx);
  } else {
    ((h4*)uout)[idx] = __builtin_convertvector(r, h4);
  }
}

extern "C" void kernel_launch(void* const* d_in, const int* in_sizes, int n_in,
                              void* d_out, int out_size, void* d_ws, size_t ws_size,
                              hipStream_t stream) {
  const float* x    = (const float*)d_in[0];
  const float* g    = (const float*)d_in[1];
  const float* dist = (const float*)d_in[2];
  const float* w1   = (const float*)d_in[3];
  const float* w2   = (const float*)d_in[4];
  const float* w3   = (const float*)d_in[5];
  const float* w4   = (const float*)d_in[6];
  const float* w5   = (const float*)d_in[7];
  const int*   src  = (const int*)d_in[8];
  const int*   dst  = (const int*)d_in[9];

  const int N = in_sizes[0] / D;
  const int E = in_sizes[2];
  const int Ehalf = E / 2;

  // ---- workspace carve: packedA+packedB adjacent (one small memset) ----
  char* ws = (char*)d_ws;
  size_t o = 0;
  unsigned long long* packedA = (unsigned long long*)(ws + o); o += align_up((size_t)N * 8, 256);
  unsigned long long* packedB = (unsigned long long*)(ws + o);
  size_t zero_end = o + (size_t)N * 8;
  o += align_up((size_t)N * 8, 256);
  unsigned short* adjA = (unsigned short*)(ws + o); o += align_up((size_t)N * CAPH * 2, 256);
  unsigned short* adjB = (unsigned short*)(ws + o); o += align_up((size_t)N * CAPH * 2, 256);
  h4* baseB = (h4*)(ws + o); o += align_up((size_t)(N + 1) * D * 2, 256);
  h4* uA    = (h4*)(ws + o); o += align_up((size_t)(N + 1) * D * 2, 256);
  h4* uB    = (h4*)(ws + o); o += align_up((size_t)(N + 1) * D * 2, 256);
  float* out = (float*)d_out;

  hipMemsetAsync(ws, 0, zero_end, stream);   // zero packedA+packedB (0.8 MB)

  const int tb = 256;
  const int eblocks = (E + tb - 1) / tb;
  const int sthreads = (N + 1) * 32;
  const int sblocks = (sthreads + tb - 1) / tb;

  fill_ell_kernel<<<eblocks, tb, 0, stream>>>(src, dst, dist, packedA, packedB,
                                              adjA, adjB, E, Ehalf);
  base_seed_kernel<<<sblocks, tb, 0, stream>>>((const v4f*)x, (const v4f*)g,
                                               packedA, packedB,
                                               w1, w2, w4, w5, baseB, uA, uB, N);

  // grid: (node chunks of 16) x 2 feature-halves; half = blockIdx & 1
  const int chunks = (N + 15) / 16;
  const int pblocks = chunks * 2;
  prop_kernel<<<pblocks, 256, 0, stream>>>(uA, baseB, packedA, packedB, adjA, adjB, w3, uB,  N, 0);
  prop_kernel<<<pblocks, 256, 0, stream>>>(uB, baseB, packedA, packedB, adjA, adjB, w3, uA,  N, 0);
  prop_kernel<<<pblocks, 256, 0, stream>>>(uA, baseB, packedA, packedB, adjA, adjB, w3, uB,  N, 0);
  prop_kernel<<<pblocks, 256, 0, stream>>>(uB, baseB, packedA, packedB, adjA, adjB, w3, uA,  N, 0);
  prop_kernel<<<pblocks, 256, 0, stream>>>(uA, baseB, packedA, packedB, adjA, adjB, w3, out, N, 1);
}